// Round 1
// baseline (552.411 us; speedup 1.0000x reference)
//
#include <hip/hip_runtime.h>
#include <math.h>

#define N 512
#define LOGN 9
#define NT 256          // threads per block
#define TC 8            // columns per block in column kernel
#define CSTRIDE (N + 2) // float2 stride per column in LDS (breaks bank alignment)

__device__ __forceinline__ float2 cmul(float2 a, float2 b) {
    return make_float2(a.x * b.x - a.y * b.y, a.x * b.y + a.y * b.x);
}
__device__ __forceinline__ float2 cadd(float2 a, float2 b) { return make_float2(a.x + b.x, a.y + b.y); }
__device__ __forceinline__ float2 csub(float2 a, float2 b) { return make_float2(a.x - b.x, a.y - b.y); }

// twiddle table: tw[k] = exp(-2*pi*i*k/N), k in [0, N/2)
__device__ __forceinline__ void make_table(float2* tw, int t) {
    // NT == N/2, so each thread fills exactly one entry
    float ang = -6.28318530717958647692f * (float)t / (float)N;
    float s, c;
    sincosf(ang, &s, &c);
    tw[t] = make_float2(c, s);
}

// ---------------- Kernel 1: forward row FFT (DIF, output bit-reversed in v) -----
__global__ __launch_bounds__(NT) void k_row_fwd(const float* __restrict__ x,
                                                float2* __restrict__ ws, int imgBase) {
    __shared__ float2 buf[N];
    __shared__ float2 tw[N / 2];
    int t = threadIdx.x;
    int img = blockIdx.x >> LOGN;    // /512
    int row = blockIdx.x & (N - 1);
    make_table(tw, t);
    const float* xr = x + ((size_t)(imgBase + img) * N + row) * N;
    buf[t]       = make_float2(xr[t], 0.f);
    buf[t + 256] = make_float2(xr[t + 256], 0.f);
    // DIF: natural in, bit-reversed out
    for (int ls = LOGN - 1; ls >= 0; --ls) {
        __syncthreads();
        int s = 1 << ls;
        int off = t & (s - 1);
        int i = ((t >> ls) << (ls + 1)) + off;
        int j = i + s;
        float2 a = buf[i], b = buf[j];
        float2 w = tw[off << (LOGN - 1 - ls)];
        buf[i] = cadd(a, b);
        buf[j] = cmul(csub(a, b), w);
    }
    __syncthreads();
    float2* o = ws + ((size_t)img * N + row) * N;
    o[t] = buf[t];
    o[t + 256] = buf[t + 256];
}

// ------- Kernel 2: column FFT (DIF) -> filter multiply -> column IFFT (DIT) ----
__global__ __launch_bounds__(NT) void k_col(float2* __restrict__ ws,
                                            const float* __restrict__ param, int imgBase) {
    __shared__ float2 buf[TC * CSTRIDE];
    __shared__ float2 tw[N / 2];
    int t = threadIdx.x;
    int img = blockIdx.x >> (LOGN - 3);  // / 64 tiles per image
    int tile = blockIdx.x & ((N / TC) - 1);
    int colBase = tile * TC;
    make_table(tw, t);
    float2* wsImg = ws + (size_t)img * N * N;

    // load 512 rows x TC cols, col-major in LDS
    for (int k = 0; k < (N * TC) / NT; ++k) {
        int lin = k * NT + t;
        int r = lin >> 3;        // / TC
        int c = lin & (TC - 1);
        buf[c * CSTRIDE + r] = wsImg[(size_t)r * N + colBase + c];
    }
    __syncthreads();

    // forward DIF along columns (u dimension)
    for (int ls = LOGN - 1; ls >= 0; --ls) {
        int s = 1 << ls;
        int off = t & (s - 1);
        int i = ((t >> ls) << (ls + 1)) + off;
        int j = i + s;
        float2 w = tw[off << (LOGN - 1 - ls)];
        for (int c = 0; c < TC; ++c) {
            float2 a = buf[c * CSTRIDE + i], b = buf[c * CSTRIDE + j];
            buf[c * CSTRIDE + i] = cadd(a, b);
            buf[c * CSTRIDE + j] = cmul(csub(a, b), w);
        }
        __syncthreads();
    }

    // pointwise filter: u = bitrev(pos), v = bitrev(col); mask computed inline
    int ch = (imgBase + img) % 3;
    const float invN2 = 1.0f / ((float)N * (float)N);
    for (int k = 0; k < (N * TC) / NT; ++k) {
        int lin = k * NT + t;
        int c = lin >> LOGN;     // / 512
        int pos = lin & (N - 1);
        int u = (int)(__brev((unsigned)pos) >> (32 - LOGN));
        int v = (int)(__brev((unsigned)(colBase + c)) >> (32 - LOGN));
        int dh = (u < 256) ? u : (512 - u);
        int dw = (v < 256) ? v : (512 - v);
        int d2 = dh * dh + dw * dw;
        float m;
        if (d2 <= 1) {
            m = 0.5f;
        } else {
            float dist = sqrtf((float)d2) * (1.0f / 256.0f);
            m = fmaxf(1.0f, 2.0f * dist);
        }
        int su = (u + 256) & (N - 1);
        int sv = (v + 256) & (N - 1);
        float p = param[((size_t)ch * N + su) * N + sv];
        float scale = m * p * invN2;
        float2 val = buf[c * CSTRIDE + pos];
        buf[c * CSTRIDE + pos] = make_float2(val.x * scale, val.y * scale);
    }
    __syncthreads();

    // inverse DIT along columns (bit-reversed in, natural out), conj twiddles
    for (int ls = 0; ls < LOGN; ++ls) {
        int s = 1 << ls;
        int off = t & (s - 1);
        int i = ((t >> ls) << (ls + 1)) + off;
        int j = i + s;
        float2 w = tw[off << (LOGN - 1 - ls)];
        float2 wc = make_float2(w.x, -w.y);
        for (int c = 0; c < TC; ++c) {
            float2 a = buf[c * CSTRIDE + i];
            float2 b = cmul(buf[c * CSTRIDE + j], wc);
            buf[c * CSTRIDE + i] = cadd(a, b);
            buf[c * CSTRIDE + j] = csub(a, b);
        }
        __syncthreads();
    }

    // store back (u natural, v still bit-reversed)
    for (int k = 0; k < (N * TC) / NT; ++k) {
        int lin = k * NT + t;
        int r = lin >> 3;
        int c = lin & (TC - 1);
        wsImg[(size_t)r * N + colBase + c] = buf[c * CSTRIDE + r];
    }
}

// ------- Kernel 3: inverse row FFT (DIT, bit-reversed in, natural out), real out
__global__ __launch_bounds__(NT) void k_row_inv(const float2* __restrict__ ws,
                                                float* __restrict__ out, int imgBase) {
    __shared__ float2 buf[N];
    __shared__ float2 tw[N / 2];
    int t = threadIdx.x;
    int img = blockIdx.x >> LOGN;
    int row = blockIdx.x & (N - 1);
    make_table(tw, t);
    const float2* i0 = ws + ((size_t)img * N + row) * N;
    buf[t] = i0[t];
    buf[t + 256] = i0[t + 256];
    for (int ls = 0; ls < LOGN; ++ls) {
        __syncthreads();
        int s = 1 << ls;
        int off = t & (s - 1);
        int i = ((t >> ls) << (ls + 1)) + off;
        int j = i + s;
        float2 w = tw[off << (LOGN - 1 - ls)];
        float2 b = cmul(buf[j], make_float2(w.x, -w.y));
        float2 a = buf[i];
        buf[i] = cadd(a, b);
        buf[j] = csub(a, b);
    }
    __syncthreads();
    float* o = out + ((size_t)(imgBase + img) * N + row) * N;
    o[t] = buf[t].x;
    o[t + 256] = buf[t + 256].x;
}

extern "C" void kernel_launch(void* const* d_in, const int* in_sizes, int n_in,
                              void* d_out, int out_size, void* d_ws, size_t ws_size,
                              hipStream_t stream) {
    const float* x = (const float*)d_in[0];
    const float* param = (const float*)d_in[1];
    float* out = (float*)d_out;
    float2* ws = (float2*)d_ws;

    const int NI = 32 * 3;  // total (batch, channel) images
    size_t perImg = (size_t)N * N * sizeof(float2);  // 2 MB per image
    int G = (int)(ws_size / perImg);
    if (G < 1) G = 1;
    if (G > NI) G = NI;

    for (int base = 0; base < NI; base += G) {
        int g = NI - base;
        if (g > G) g = G;
        k_row_fwd<<<dim3(g * N), dim3(NT), 0, stream>>>(x, ws, base);
        k_col<<<dim3(g * (N / TC)), dim3(NT), 0, stream>>>(ws, param, base);
        k_row_inv<<<dim3(g * N), dim3(NT), 0, stream>>>(ws, out, base);
    }
}

// Round 2
// 454.545 us; speedup vs baseline: 1.2153x; 1.2153x over previous
//
#include <hip/hip_runtime.h>
#include <math.h>

#define N 512
#define LOGN 9
#define CS 514   // float2 stride per column in k_col LDS tile

__device__ __forceinline__ float2 cadd(float2 a, float2 b) { return make_float2(a.x + b.x, a.y + b.y); }
__device__ __forceinline__ float2 csub(float2 a, float2 b) { return make_float2(a.x - b.x, a.y - b.y); }
__device__ __forceinline__ float2 cmul(float2 a, float2 b) {
    return make_float2(a.x * b.x - a.y * b.y, a.x * b.y + a.y * b.x);
}
__device__ __forceinline__ float2 shfl_xor_c(float2 v, int mask) {
    return make_float2(__shfl_xor(v.x, mask), __shfl_xor(v.y, mask));
}
__device__ __forceinline__ int brev9(int x) { return (int)(__brev((unsigned)x) >> 23); }

// DIF butterfly: a' = a+b ; b' = (a-b)*w
__device__ __forceinline__ void bf_dif(float2& a, float2& b, float2 w) {
    float2 t = csub(a, b);
    a = cadd(a, b);
    b = cmul(t, w);
}
// DIT butterfly (inverse, wc already conjugated): a' = a + b*wc ; b' = a - b*wc
__device__ __forceinline__ void bf_dit(float2& a, float2& b, float2 wc) {
    float2 t = cmul(b, wc);
    b = csub(a, t);
    a = cadd(a, t);
}

// tw[k] = exp(-2*pi*i*k/512), k in [0,256)
__device__ __forceinline__ void fill_tw_entry(float2* tw, int k) {
    float ang = -6.28318530717958647692f * (float)k / (float)N;
    float s, c;
    sincosf(ang, &s, &c);
    tw[k] = make_float2(c, s);
}

// Forward 512-pt DIF, registers: storage idx = r*64 + l. Natural in, bit-rev out.
__device__ __forceinline__ void fft512_fwd(float2 v[8], int l, const float2* tw) {
    // ls=8: pairs (r, r+4), off = r*64+l, twidx = off
    for (int r = 0; r < 4; ++r) bf_dif(v[r], v[r + 4], tw[r * 64 + l]);
    // ls=7: pairs differ in reg bit1, off = (r&1)*64+l, twidx = off<<1
    {
        float2 w0 = tw[l << 1];
        float2 w1 = tw[(64 + l) << 1];
        bf_dif(v[0], v[2], w0); bf_dif(v[1], v[3], w1);
        bf_dif(v[4], v[6], w0); bf_dif(v[5], v[7], w1);
    }
    // ls=6: pairs differ in reg bit0, off = l, twidx = l<<2
    {
        float2 w = tw[l << 2];
        bf_dif(v[0], v[1], w); bf_dif(v[2], v[3], w);
        bf_dif(v[4], v[5], w); bf_dif(v[6], v[7], w);
    }
    // ls=5..0: lane-bit stages via shfl_xor
    for (int ls = 5; ls >= 0; --ls) {
        int s = 1 << ls;
        bool hi = (l & s) != 0;
        float2 w = tw[(l & (s - 1)) << (8 - ls)];
        for (int r = 0; r < 8; ++r) {
            float2 m = v[r];
            float2 o = shfl_xor_c(m, s);
            v[r] = hi ? cmul(csub(o, m), w) : cadd(m, o);
        }
    }
}

// Inverse 512-pt DIT, registers. Bit-rev in, natural out. Twiddles conjugated.
__device__ __forceinline__ void fft512_inv(float2 v[8], int l, const float2* tw) {
    for (int ls = 0; ls <= 5; ++ls) {
        int s = 1 << ls;
        bool hi = (l & s) != 0;
        float2 w = tw[(l & (s - 1)) << (8 - ls)];
        float2 wc = make_float2(w.x, -w.y);
        for (int r = 0; r < 8; ++r) {
            float2 m = hi ? cmul(v[r], wc) : v[r];
            float2 o = shfl_xor_c(m, s);
            v[r] = hi ? csub(o, m) : cadd(m, o);
        }
    }
    // ls=6
    {
        float2 w = tw[l << 2];
        float2 wc = make_float2(w.x, -w.y);
        bf_dit(v[0], v[1], wc); bf_dit(v[2], v[3], wc);
        bf_dit(v[4], v[5], wc); bf_dit(v[6], v[7], wc);
    }
    // ls=7
    {
        float2 w0 = tw[l << 1];
        float2 w1 = tw[(64 + l) << 1];
        float2 wc0 = make_float2(w0.x, -w0.y);
        float2 wc1 = make_float2(w1.x, -w1.y);
        bf_dit(v[0], v[2], wc0); bf_dit(v[1], v[3], wc1);
        bf_dit(v[4], v[6], wc0); bf_dit(v[5], v[7], wc1);
    }
    // ls=8
    for (int r = 0; r < 4; ++r) {
        float2 w = tw[r * 64 + l];
        bf_dit(v[r], v[r + 4], make_float2(w.x, -w.y));
    }
}

// -------- Kernel 1: forward row FFT. 256 thr = 4 waves = 4 rows/block. --------
__global__ __launch_bounds__(256) void k_row_fwd(const float* __restrict__ x,
                                                 float2* __restrict__ ws, int imgBase) {
    __shared__ float2 tw[N / 2];
    int t = threadIdx.x;
    int l = t & 63, wv = t >> 6;
    fill_tw_entry(tw, t);
    __syncthreads();
    int img = blockIdx.x >> 7;
    int row = ((blockIdx.x & 127) << 2) + wv;
    const float* xr = x + ((size_t)(imgBase + img) * N + row) * N;
    float2 v[8];
#pragma unroll
    for (int r = 0; r < 8; ++r) v[r] = make_float2(xr[r * 64 + l], 0.f);
    fft512_fwd(v, l, tw);
    float2* o = ws + ((size_t)img * N + row) * N;
#pragma unroll
    for (int r = 0; r < 8; ++r) o[r * 64 + l] = v[r];
}

// -------- Kernel 2: column FFT -> filter -> column IFFT. 512 thr, 8 cols. ----
__global__ __launch_bounds__(512) void k_col(float2* __restrict__ ws,
                                             const float* __restrict__ param, int imgBase) {
    __shared__ float2 tile[8 * CS];
    __shared__ float2 tw[N / 2];
    int t = threadIdx.x;
    int l = t & 63, wv = t >> 6;
    if (t < 256) fill_tw_entry(tw, t);
    int img = blockIdx.x >> 6;
    int colBase = (blockIdx.x & 63) << 3;
    float2* wsImg = ws + (size_t)img * (size_t)(N * N);

    // coalesced tile load: 4096 float2, c fastest (64 B runs per 8 lanes)
#pragma unroll
    for (int k = 0; k < 8; ++k) {
        int lin = (k << 9) + t;
        int r = lin >> 3, c = lin & 7;
        tile[c * CS + r] = wsImg[(size_t)r * N + colBase + c];
    }
    __syncthreads();

    float2 v[8];
    const float2* mycol = tile + wv * CS;
#pragma unroll
    for (int r = 0; r < 8; ++r) v[r] = mycol[r * 64 + l];

    fft512_fwd(v, l, tw);

    // pointwise filter in bit-reversed coords
    int ch = (imgBase + img) % 3;
    int col = colBase + wv;
    int vf = brev9(col);
    int dw = (vf < 256) ? vf : (512 - vf);
    int sv = (vf + 256) & (N - 1);
    const float invN2 = 1.0f / ((float)N * (float)N);
#pragma unroll
    for (int r = 0; r < 8; ++r) {
        int idx = r * 64 + l;
        int u = brev9(idx);
        int dh = (u < 256) ? u : (512 - u);
        int d2 = dh * dh + dw * dw;
        float m = (d2 <= 1) ? 0.5f : fmaxf(1.0f, sqrtf((float)d2) * (2.0f / 256.0f));
        int su = (u + 256) & (N - 1);
        float p = param[((size_t)ch * N + su) * N + sv];
        float sc = m * p * invN2;
        v[r].x *= sc;
        v[r].y *= sc;
    }

    fft512_inv(v, l, tw);

    float2* mycolw = tile + wv * CS;
#pragma unroll
    for (int r = 0; r < 8; ++r) mycolw[r * 64 + l] = v[r];
    __syncthreads();

#pragma unroll
    for (int k = 0; k < 8; ++k) {
        int lin = (k << 9) + t;
        int r = lin >> 3, c = lin & 7;
        wsImg[(size_t)r * N + colBase + c] = tile[c * CS + r];
    }
}

// -------- Kernel 3: inverse row FFT, write real part. 4 rows/block. ----------
__global__ __launch_bounds__(256) void k_row_inv(const float2* __restrict__ ws,
                                                 float* __restrict__ out, int imgBase) {
    __shared__ float2 tw[N / 2];
    int t = threadIdx.x;
    int l = t & 63, wv = t >> 6;
    fill_tw_entry(tw, t);
    __syncthreads();
    int img = blockIdx.x >> 7;
    int row = ((blockIdx.x & 127) << 2) + wv;
    const float2* i0 = ws + ((size_t)img * N + row) * N;
    float2 v[8];
#pragma unroll
    for (int r = 0; r < 8; ++r) v[r] = i0[r * 64 + l];
    fft512_inv(v, l, tw);
    float* o = out + ((size_t)(imgBase + img) * N + row) * N;
#pragma unroll
    for (int r = 0; r < 8; ++r) o[r * 64 + l] = v[r].x;
}

extern "C" void kernel_launch(void* const* d_in, const int* in_sizes, int n_in,
                              void* d_out, int out_size, void* d_ws, size_t ws_size,
                              hipStream_t stream) {
    const float* x = (const float*)d_in[0];
    const float* param = (const float*)d_in[1];
    float* out = (float*)d_out;
    float2* ws = (float2*)d_ws;

    const int NI = 32 * 3;
    size_t perImg = (size_t)N * N * sizeof(float2);  // 2 MB per image
    int G = (int)(ws_size / perImg);
    if (G < 1) G = 1;
    if (G > NI) G = NI;

    for (int base = 0; base < NI; base += G) {
        int g = NI - base;
        if (g > G) g = G;
        k_row_fwd<<<dim3(g * 128), dim3(256), 0, stream>>>(x, ws, base);
        k_col<<<dim3(g * 64), dim3(512), 0, stream>>>(ws, param, base);
        k_row_inv<<<dim3(g * 128), dim3(256), 0, stream>>>(ws, out, base);
    }
}

// Round 3
// 400.481 us; speedup vs baseline: 1.3794x; 1.1350x over previous
//
#include <hip/hip_runtime.h>
#include <math.h>

#define N 512
#define CS 514
#define S8 0.70710678118654752440f

__device__ __forceinline__ float2 cadd(float2 a, float2 b){ return make_float2(a.x+b.x, a.y+b.y); }
__device__ __forceinline__ float2 csub(float2 a, float2 b){ return make_float2(a.x-b.x, a.y-b.y); }
__device__ __forceinline__ float2 cmul(float2 a, float2 b){
    return make_float2(fmaf(a.x,b.x,-(a.y*b.y)), fmaf(a.x,b.y, a.y*b.x));
}
template<int INV> __device__ __forceinline__ float2 rot90(float2 a){
    return INV ? make_float2(-a.y, a.x) : make_float2(a.y, -a.x);          // *(∓i)
}
template<int INV> __device__ __forceinline__ float2 rotW1(float2 a){       // *W8^{±1}
    return INV ? make_float2(S8*(a.x-a.y), S8*(a.x+a.y))
               : make_float2(S8*(a.x+a.y), S8*(a.y-a.x));
}
template<int INV> __device__ __forceinline__ float2 rotW3(float2 a){       // *W8^{±3}
    return INV ? make_float2(-S8*(a.x+a.y), S8*(a.x-a.y))
               : make_float2(S8*(a.y-a.x), -S8*(a.x+a.y));
}

// 8-pt FFT in registers, natural in, natural out (bit-rev folded into reg labels)
template<int INV>
__device__ __forceinline__ void fft8(float2 v[8]) {
    float2 t0 = cadd(v[0],v[4]), t4 = csub(v[0],v[4]);
    float2 t1 = cadd(v[1],v[5]), t5 = rotW1<INV>(csub(v[1],v[5]));
    float2 t2 = cadd(v[2],v[6]), t6 = rot90<INV>(csub(v[2],v[6]));
    float2 t3 = cadd(v[3],v[7]), t7 = rotW3<INV>(csub(v[3],v[7]));
    float2 u0 = cadd(t0,t2), u2 = csub(t0,t2);
    float2 u1 = cadd(t1,t3), u3 = rot90<INV>(csub(t1,t3));
    float2 u4 = cadd(t4,t6), u6 = csub(t4,t6);
    float2 u5 = cadd(t5,t7), u7 = rot90<INV>(csub(t5,t7));
    v[0]=cadd(u0,u1); v[4]=csub(u0,u1);
    v[2]=cadd(u2,u3); v[6]=csub(u2,u3);
    v[1]=cadd(u4,u5); v[5]=csub(u4,u5);
    v[3]=cadd(u6,u7); v[7]=csub(u6,u7);
}

// v[q] *= w1^q  (short power chains, depth<=2)
__device__ __forceinline__ void apply_pow(float2 v[8], float2 w1) {
    float2 w2 = cmul(w1,w1);
    float2 w3 = cmul(w2,w1);
    float2 w4 = cmul(w2,w2);
    v[1]=cmul(v[1],w1); v[2]=cmul(v[2],w2); v[3]=cmul(v[3],w3); v[4]=cmul(v[4],w4);
    v[5]=cmul(v[5],cmul(w4,w1));
    v[6]=cmul(v[6],cmul(w4,w2));
    v[7]=cmul(v[7],cmul(w4,w3));
}

// tw[k] = exp(-2*pi*i*k/512), k in [0,512)
__device__ __forceinline__ void fill_tw(float2* tw, int k) {
    float ang = -6.28318530717958647692f * (float)k / (float)N;
    float s, c; sincosf(ang, &s, &c);
    tw[k] = make_float2(c, s);
}

// 512-pt FFT per wave. Input: v[a] = x[a*64 + l] (natural). Output: lane l holds
// X[64*r + l] in reg r (natural order). sc: 512-float2 wave-private LDS scratch.
__device__ __forceinline__ void fft512_fwd(float2 v[8], int l, float2* sc, const float2* tw) {
    int hi = l >> 3, lo = l & 7;
    fft8<0>(v);                        // over a -> q
    apply_pow(v, tw[l]);               // W512^{l*q}
#pragma unroll
    for (int q = 0; q < 8; ++q) sc[q*64 + ((hi ^ q) << 3) + lo] = v[q];       // T1 write
#pragma unroll
    for (int b = 0; b < 8; ++b) v[b] = sc[hi*64 + ((b ^ hi) << 3) + lo];      // T1 read
    fft8<0>(v);                        // over b -> q2
    apply_pow(v, tw[lo << 3]);         // W64^{c*q2}
#pragma unroll
    for (int q2 = 0; q2 < 8; ++q2) sc[q2*64 + ((hi ^ q2) << 3) + (lo ^ hi)] = v[q2]; // T2 write
#pragma unroll
    for (int c = 0; c < 8; ++c) v[c] = sc[hi*64 + ((lo ^ hi) << 3) + (c ^ lo)];      // T2 read
    fft8<0>(v);                        // over c -> q3
}

// Inverse (unnormalized): input lane l reg r = X[64*r + l]; output v[a] = x[64*a + l].
__device__ __forceinline__ void fft512_inv(float2 v[8], int l, float2* sc, const float2* tw) {
    int hi = l >> 3, lo = l & 7;
    fft8<1>(v);                        // over q3 -> c
#pragma unroll
    for (int c = 0; c < 8; ++c) sc[hi*64 + ((lo ^ hi) << 3) + (c ^ lo)] = v[c];      // T2^-1 write
#pragma unroll
    for (int q2 = 0; q2 < 8; ++q2) v[q2] = sc[q2*64 + ((hi ^ q2) << 3) + (lo ^ hi)]; // T2^-1 read
    {
        float2 w = tw[lo << 3];
        apply_pow(v, make_float2(w.x, -w.y));   // conj W64^{c*q2}
    }
    fft8<1>(v);                        // over q2 -> b
#pragma unroll
    for (int b = 0; b < 8; ++b) sc[hi*64 + ((b ^ hi) << 3) + lo] = v[b];      // T1^-1 write
#pragma unroll
    for (int q = 0; q < 8; ++q) v[q] = sc[q*64 + ((hi ^ q) << 3) + lo];       // T1^-1 read
    {
        float2 w = tw[l];
        apply_pow(v, make_float2(w.x, -w.y));   // conj W512^{l*q}
    }
    fft8<1>(v);                        // over q -> a
}

// -------- Kernel 1: forward row FFT. 256 thr = 4 waves = 4 rows/block. --------
__global__ __launch_bounds__(256) void k_row_fwd(const float* __restrict__ x,
                                                 float2* __restrict__ ws, int imgBase) {
    __shared__ float2 scr[4 * 512];
    __shared__ float2 tw[512];
    int t = threadIdx.x;
    int l = t & 63, wv = t >> 6;
    fill_tw(tw, t); fill_tw(tw, t + 256);
    __syncthreads();
    int img = blockIdx.x >> 7;
    int row = ((blockIdx.x & 127) << 2) + wv;
    const float* xr = x + ((size_t)(imgBase + img) * N + row) * N;
    float2 v[8];
#pragma unroll
    for (int a = 0; a < 8; ++a) v[a] = make_float2(xr[a * 64 + l], 0.f);
    fft512_fwd(v, l, scr + wv * 512, tw);
    float2* o = ws + ((size_t)img * N + row) * N;
#pragma unroll
    for (int r = 0; r < 8; ++r) o[r * 64 + l] = v[r];   // natural freq order
}

// -------- Kernel 2: column FFT -> filter -> column IFFT. 512 thr, 8 cols. ----
__global__ __launch_bounds__(512) void k_col(float2* __restrict__ ws,
                                             const float* __restrict__ param, int imgBase) {
    __shared__ float2 tile[8 * CS];   // 8 columns, stride 514; doubles as FFT scratch
    __shared__ float2 tw[512];
    int t = threadIdx.x;
    int l = t & 63, wv = t >> 6;
    fill_tw(tw, t);
    int img = blockIdx.x >> 6;
    int colBase = (blockIdx.x & 63) << 3;
    float2* wsImg = ws + (size_t)img * (size_t)(N * N);

    // coalesced tile load (c fastest): 512B per wave-instruction
#pragma unroll
    for (int k = 0; k < 8; ++k) {
        int lin = (k << 9) + t;
        int r = lin >> 3, c = lin & 7;
        tile[c * CS + r] = wsImg[(size_t)r * N + colBase + c];
    }
    __syncthreads();

    float2* sc = tile + wv * CS;   // wave-private column data / scratch
    float2 v[8];
#pragma unroll
    for (int a = 0; a < 8; ++a) v[a] = sc[a * 64 + l];

    fft512_fwd(v, l, sc, tw);

    // pointwise filter, natural coords: reg r holds row-freq u = 64r + l
    int ch = (imgBase + img) % 3;
    int col = colBase + wv;
    int dw = (col < 256) ? col : (512 - col);
    int sv = (col + 256) & (N - 1);
    const float invN2 = 1.0f / ((float)N * (float)N);
#pragma unroll
    for (int r = 0; r < 8; ++r) {
        int u = r * 64 + l;
        int dh = (u < 256) ? u : (512 - u);
        int d2 = dh * dh + dw * dw;
        float m = (d2 <= 1) ? 0.5f : fmaxf(1.0f, sqrtf((float)d2) * (2.0f / 256.0f));
        int su = (u + 256) & (N - 1);
        float p = param[((size_t)ch * N + su) * N + sv];
        float scf = m * p * invN2;
        v[r].x *= scf; v[r].y *= scf;
    }

    fft512_inv(v, l, sc, tw);

#pragma unroll
    for (int a = 0; a < 8; ++a) sc[a * 64 + l] = v[a];
    __syncthreads();

#pragma unroll
    for (int k = 0; k < 8; ++k) {
        int lin = (k << 9) + t;
        int r = lin >> 3, c = lin & 7;
        wsImg[(size_t)r * N + colBase + c] = tile[c * CS + r];
    }
}

// -------- Kernel 3: inverse row FFT, write real part. 4 rows/block. ----------
__global__ __launch_bounds__(256) void k_row_inv(const float2* __restrict__ ws,
                                                 float* __restrict__ out, int imgBase) {
    __shared__ float2 scr[4 * 512];
    __shared__ float2 tw[512];
    int t = threadIdx.x;
    int l = t & 63, wv = t >> 6;
    fill_tw(tw, t); fill_tw(tw, t + 256);
    __syncthreads();
    int img = blockIdx.x >> 7;
    int row = ((blockIdx.x & 127) << 2) + wv;
    const float2* i0 = ws + ((size_t)img * N + row) * N;
    float2 v[8];
#pragma unroll
    for (int r = 0; r < 8; ++r) v[r] = i0[r * 64 + l];
    fft512_inv(v, l, scr + wv * 512, tw);
    float* o = out + ((size_t)(imgBase + img) * N + row) * N;
#pragma unroll
    for (int a = 0; a < 8; ++a) o[a * 64 + l] = v[a].x;
}

extern "C" void kernel_launch(void* const* d_in, const int* in_sizes, int n_in,
                              void* d_out, int out_size, void* d_ws, size_t ws_size,
                              hipStream_t stream) {
    const float* x = (const float*)d_in[0];
    const float* param = (const float*)d_in[1];
    float* out = (float*)d_out;
    float2* ws = (float2*)d_ws;

    const int NI = 32 * 3;
    size_t perImg = (size_t)N * N * sizeof(float2);
    int G = (int)(ws_size / perImg);
    if (G < 1) G = 1;
    if (G > NI) G = NI;

    for (int base = 0; base < NI; base += G) {
        int g = NI - base;
        if (g > G) g = G;
        k_row_fwd<<<dim3(g * 128), dim3(256), 0, stream>>>(x, ws, base);
        k_col<<<dim3(g * 64), dim3(512), 0, stream>>>(ws, param, base);
        k_row_inv<<<dim3(g * 128), dim3(256), 0, stream>>>(ws, out, base);
    }
}

// Round 4
// 272.870 us; speedup vs baseline: 2.0244x; 1.4677x over previous
//
#include <hip/hip_runtime.h>
#include <math.h>

#define N 512
#define CS 514
#define S8 0.70710678118654752440f

__device__ __forceinline__ float2 cadd(float2 a, float2 b){ return make_float2(a.x+b.x, a.y+b.y); }
__device__ __forceinline__ float2 csub(float2 a, float2 b){ return make_float2(a.x-b.x, a.y-b.y); }
__device__ __forceinline__ float2 cmul(float2 a, float2 b){
    return make_float2(fmaf(a.x,b.x,-(a.y*b.y)), fmaf(a.x,b.y, a.y*b.x));
}
template<int INV> __device__ __forceinline__ float2 rot90(float2 a){
    return INV ? make_float2(-a.y, a.x) : make_float2(a.y, -a.x);          // *(∓i)
}
template<int INV> __device__ __forceinline__ float2 rotW1(float2 a){       // *W8^{±1}
    return INV ? make_float2(S8*(a.x-a.y), S8*(a.x+a.y))
               : make_float2(S8*(a.x+a.y), S8*(a.y-a.x));
}
template<int INV> __device__ __forceinline__ float2 rotW3(float2 a){       // *W8^{±3}
    return INV ? make_float2(-S8*(a.x+a.y), S8*(a.x-a.y))
               : make_float2(S8*(a.y-a.x), -S8*(a.x+a.y));
}

template<int INV>
__device__ __forceinline__ void fft8(float2 v[8]) {
    float2 t0 = cadd(v[0],v[4]), t4 = csub(v[0],v[4]);
    float2 t1 = cadd(v[1],v[5]), t5 = rotW1<INV>(csub(v[1],v[5]));
    float2 t2 = cadd(v[2],v[6]), t6 = rot90<INV>(csub(v[2],v[6]));
    float2 t3 = cadd(v[3],v[7]), t7 = rotW3<INV>(csub(v[3],v[7]));
    float2 u0 = cadd(t0,t2), u2 = csub(t0,t2);
    float2 u1 = cadd(t1,t3), u3 = rot90<INV>(csub(t1,t3));
    float2 u4 = cadd(t4,t6), u6 = csub(t4,t6);
    float2 u5 = cadd(t5,t7), u7 = rot90<INV>(csub(t5,t7));
    v[0]=cadd(u0,u1); v[4]=csub(u0,u1);
    v[2]=cadd(u2,u3); v[6]=csub(u2,u3);
    v[1]=cadd(u4,u5); v[5]=csub(u4,u5);
    v[3]=cadd(u6,u7); v[7]=csub(u6,u7);
}

__device__ __forceinline__ void apply_pow(float2 v[8], float2 w1) {
    float2 w2 = cmul(w1,w1);
    float2 w3 = cmul(w2,w1);
    float2 w4 = cmul(w2,w2);
    v[1]=cmul(v[1],w1); v[2]=cmul(v[2],w2); v[3]=cmul(v[3],w3); v[4]=cmul(v[4],w4);
    v[5]=cmul(v[5],cmul(w4,w1));
    v[6]=cmul(v[6],cmul(w4,w2));
    v[7]=cmul(v[7],cmul(w4,w3));
}

// tw[k] = exp(-2*pi*i*k/512)
__device__ __forceinline__ void fill_tw(float2* tw, int k) {
    float ang = -6.28318530717958647692f * (float)k / (float)N;
    float s, c; sincosf(ang, &s, &c);
    tw[k] = make_float2(c, s);
}

// 512-pt FFT per wave, radix-8. In: v[a]=x[64a+l] natural. Out: reg r = X[64r+l].
__device__ __forceinline__ void fft512_fwd(float2 v[8], int l, float2* sc, const float2* tw) {
    int hi = l >> 3, lo = l & 7;
    fft8<0>(v);
    apply_pow(v, tw[l]);
#pragma unroll
    for (int q = 0; q < 8; ++q) sc[q*64 + ((hi ^ q) << 3) + lo] = v[q];
#pragma unroll
    for (int b = 0; b < 8; ++b) v[b] = sc[hi*64 + ((b ^ hi) << 3) + lo];
    fft8<0>(v);
    apply_pow(v, tw[lo << 3]);
#pragma unroll
    for (int q2 = 0; q2 < 8; ++q2) sc[q2*64 + ((hi ^ q2) << 3) + (lo ^ hi)] = v[q2];
#pragma unroll
    for (int c = 0; c < 8; ++c) v[c] = sc[hi*64 + ((lo ^ hi) << 3) + (c ^ lo)];
    fft8<0>(v);
}

__device__ __forceinline__ void fft512_inv(float2 v[8], int l, float2* sc, const float2* tw) {
    int hi = l >> 3, lo = l & 7;
    fft8<1>(v);
#pragma unroll
    for (int c = 0; c < 8; ++c) sc[hi*64 + ((lo ^ hi) << 3) + (c ^ lo)] = v[c];
#pragma unroll
    for (int q2 = 0; q2 < 8; ++q2) v[q2] = sc[q2*64 + ((hi ^ q2) << 3) + (lo ^ hi)];
    {
        float2 w = tw[lo << 3];
        apply_pow(v, make_float2(w.x, -w.y));
    }
    fft8<1>(v);
#pragma unroll
    for (int b = 0; b < 8; ++b) sc[hi*64 + ((b ^ hi) << 3) + lo] = v[b];
#pragma unroll
    for (int q = 0; q < 8; ++q) v[q] = sc[q*64 + ((hi ^ q) << 3) + lo];
    {
        float2 w = tw[l];
        apply_pow(v, make_float2(w.x, -w.y));
    }
    fft8<1>(v);
}

// -------- Kernel 0: precompute symmetrized filter, v-major layout ------------
// filt[c][v][u] = mask(u,v) * (param[c,sh(u),sh(v)] + param[c,sh(-u),sh(-v)])/2 / N^2
__global__ __launch_bounds__(512) void k_filt(const float* __restrict__ param,
                                              float* __restrict__ filt) {
    int c = blockIdx.x >> 9;
    int vv = blockIdx.x & 511;
    int u = threadIdx.x;
    int dh = (u < 256) ? u : (512 - u);
    int dw = (vv < 256) ? vv : (512 - vv);
    int d2 = dh * dh + dw * dw;
    float m = (d2 <= 1) ? 0.5f : fmaxf(1.0f, sqrtf((float)d2) * (2.0f / 256.0f));
    int su  = (u + 256) & 511,  sv  = (vv + 256) & 511;
    int su2 = (256 - u) & 511,  sv2 = (256 - vv) & 511;
    float p  = param[((size_t)c * N + su)  * N + sv];
    float p2 = param[((size_t)c * N + su2) * N + sv2];
    const float invN2 = 1.0f / ((float)N * (float)N);
    filt[(((size_t)c << 9) + vv) * N + u] = m * 0.5f * (p + p2) * invN2;
}

// -------- Kernel 1: forward row FFT of packed pair (A + iB). 4 rows/block. ---
__global__ __launch_bounds__(256) void k_row_fwd(const float* __restrict__ x,
                                                 float2* __restrict__ ws, int pairBase) {
    __shared__ float2 scr[4 * 512];
    __shared__ float2 tw[512];
    int t = threadIdx.x;
    int l = t & 63, wv = t >> 6;
    fill_tw(tw, t); fill_tw(tw, t + 256);
    __syncthreads();
    int pr = blockIdx.x >> 7;               // pair within chunk
    int row = ((blockIdx.x & 127) << 2) + wv;
    int pair = pairBase + pr;               // imgA = pair, imgB = pair + 48 (same channel)
    const float* xa = x + ((size_t)pair * N + row) * N;
    const float* xb = x + ((size_t)(pair + 48) * N + row) * N;
    float2 v[8];
#pragma unroll
    for (int a = 0; a < 8; ++a) v[a] = make_float2(xa[a * 64 + l], xb[a * 64 + l]);
    fft512_fwd(v, l, scr + wv * 512, tw);
    float2* o = ws + ((size_t)pr * N + row) * N;
#pragma unroll
    for (int r = 0; r < 8; ++r) o[r * 64 + l] = v[r];
}

// -------- Kernel 2: column FFT -> filter -> column IFFT. 512 thr, 8 cols. ----
__global__ __launch_bounds__(512) void k_col(float2* __restrict__ ws,
                                             const float* __restrict__ filt, int pairBase) {
    __shared__ float2 tile[8 * CS];
    __shared__ float2 tw[512];
    int t = threadIdx.x;
    int l = t & 63, wv = t >> 6;
    fill_tw(tw, t);
    int pr = blockIdx.x >> 6;
    int colBase = (blockIdx.x & 63) << 3;
    float2* wsImg = ws + (size_t)pr * (size_t)(N * N);

#pragma unroll
    for (int k = 0; k < 8; ++k) {
        int lin = (k << 9) + t;
        int r = lin >> 3, c = lin & 7;
        tile[c * CS + r] = wsImg[(size_t)r * N + colBase + c];
    }
    __syncthreads();

    float2* sc = tile + wv * CS;
    float2 v[8];
#pragma unroll
    for (int a = 0; a < 8; ++a) v[a] = sc[a * 64 + l];

    fft512_fwd(v, l, sc, tw);

    // symmetrized filter, contiguous per wave: filt[c][col][u], u = 64r + l
    int ch = (pairBase + pr) % 3;
    int col = colBase + wv;
    const float* fcol = filt + (((size_t)ch << 9) + col) * N;
#pragma unroll
    for (int r = 0; r < 8; ++r) {
        float f = fcol[r * 64 + l];
        v[r].x *= f; v[r].y *= f;
    }

    fft512_inv(v, l, sc, tw);

#pragma unroll
    for (int a = 0; a < 8; ++a) sc[a * 64 + l] = v[a];
    __syncthreads();

#pragma unroll
    for (int k = 0; k < 8; ++k) {
        int lin = (k << 9) + t;
        int r = lin >> 3, c = lin & 7;
        wsImg[(size_t)r * N + colBase + c] = tile[c * CS + r];
    }
}

// -------- Kernel 3: inverse row FFT; Re -> imgA, Im -> imgB. 4 rows/block. ---
__global__ __launch_bounds__(256) void k_row_inv(const float2* __restrict__ ws,
                                                 float* __restrict__ out, int pairBase) {
    __shared__ float2 scr[4 * 512];
    __shared__ float2 tw[512];
    int t = threadIdx.x;
    int l = t & 63, wv = t >> 6;
    fill_tw(tw, t); fill_tw(tw, t + 256);
    __syncthreads();
    int pr = blockIdx.x >> 7;
    int row = ((blockIdx.x & 127) << 2) + wv;
    int pair = pairBase + pr;
    const float2* i0 = ws + ((size_t)pr * N + row) * N;
    float2 v[8];
#pragma unroll
    for (int r = 0; r < 8; ++r) v[r] = i0[r * 64 + l];
    fft512_inv(v, l, scr + wv * 512, tw);
    float* oa = out + ((size_t)pair * N + row) * N;
    float* ob = out + ((size_t)(pair + 48) * N + row) * N;
#pragma unroll
    for (int a = 0; a < 8; ++a) { oa[a * 64 + l] = v[a].x; ob[a * 64 + l] = v[a].y; }
}

extern "C" void kernel_launch(void* const* d_in, const int* in_sizes, int n_in,
                              void* d_out, int out_size, void* d_ws, size_t ws_size,
                              hipStream_t stream) {
    const float* x = (const float*)d_in[0];
    const float* param = (const float*)d_in[1];
    float* out = (float*)d_out;

    float* filt = (float*)d_ws;                       // 3*512*512 floats = 3 MB
    const size_t filtElems = (size_t)3 * N * N;
    float2* ws = (float2*)((char*)d_ws + filtElems * sizeof(float));

    const int NP = 48;                                // image pairs (A=i, B=i+48)
    size_t perImg = (size_t)N * N * sizeof(float2);   // 2 MB per pair
    size_t avail = (ws_size > filtElems * sizeof(float)) ? ws_size - filtElems * sizeof(float) : 0;
    int G = (int)(avail / perImg);
    if (G < 1) G = 1;
    if (G > NP) G = NP;

    k_filt<<<dim3(3 * N), dim3(N), 0, stream>>>(param, filt);

    for (int base = 0; base < NP; base += G) {
        int g = NP - base;
        if (g > G) g = G;
        k_row_fwd<<<dim3(g * 128), dim3(256), 0, stream>>>(x, ws, base);
        k_col<<<dim3(g * 64), dim3(512), 0, stream>>>(ws, filt, base);
        k_row_inv<<<dim3(g * 128), dim3(256), 0, stream>>>(ws, out, base);
    }
}